// Round 3
// baseline (205.954 us; speedup 1.0000x reference)
//
#include <hip/hip_runtime.h>
#include <hip/hip_bf16.h>

#define N 1024
#define D 64

typedef __attribute__((ext_vector_type(8))) short bf16x8;
typedef __attribute__((ext_vector_type(4))) float f32x4;

__device__ __forceinline__ unsigned short f2b(float v) {
  unsigned u = __float_as_uint(v);
  u += 0x7fffu + ((u >> 16) & 1u);
  return (unsigned short)(u >> 16);
}
// compiler-fusable bf16 pack (emits v_cvt_pk_bf16_f32 for the pair)
__device__ __forceinline__ unsigned pk2(float a, float b) {
  union { __hip_bfloat162 h; unsigned u; } r;
  r.h = __hip_bfloat162(__float2bfloat16(a), __float2bfloat16(b));
  return r.u;
}
__device__ __forceinline__ float silu_f(float x) { return x / (1.f + __expf(-x)); }

// ---------------- K1: LN1 + QKV projection ----------------
__global__ __launch_bounds__(64) void k_ln1_qkv(
    const float* __restrict__ feats, const float* __restrict__ g, const float* __restrict__ b,
    const float* __restrict__ qkv_w, float* __restrict__ xn, float* __restrict__ qkv) {
  const int i = blockIdx.x, t = threadIdx.x;
  float v = feats[i * D + t];
  float s = v;
#pragma unroll
  for (int off = 32; off; off >>= 1) s += __shfl_xor(s, off);
  const float m = s * (1.0f / 64.0f);
  const float dv = v - m;
  float vs = dv * dv;
#pragma unroll
  for (int off = 32; off; off >>= 1) vs += __shfl_xor(vs, off);
  const float var = vs * (1.0f / 64.0f);
  const float xv = dv * rsqrtf(var + 1e-5f) * g[t] + b[t];
  xn[i * D + t] = xv;
  __shared__ float xs[D];
  xs[t] = xv;
  __syncthreads();
#pragma unroll
  for (int c = 0; c < 3; ++c) {
    const int col = t + c * 64;
    float acc = 0.f;
#pragma unroll 8
    for (int k = 0; k < D; ++k) acc += xs[k] * qkv_w[k * 192 + col];
    qkv[i * 192 + col] = acc;
  }
}

// ---------------- K2: attention + mean-attn + out-proj + residual ----------------
__global__ __launch_bounds__(256) void k_attn(
    const float* __restrict__ qkv, const float* __restrict__ xn,
    const float* __restrict__ out_w, const float* __restrict__ out_b,
    float* __restrict__ x1, float* __restrict__ meanattn) {
  const int i = blockIdx.x, t = threadIdx.x;
  const int lane = t & 63, w = t >> 6;
  __shared__ float sc[4][N];
  __shared__ float qi[D];
  __shared__ float wred[4][4];
  __shared__ float hstat[8];
  __shared__ float red[256];
  __shared__ float msgv[64];
  if (t < D) qi[t] = qkv[i * 192 + t];
  __syncthreads();
  float lm[4] = {-1e30f, -1e30f, -1e30f, -1e30f};
  for (int j = t; j < N; j += 256) {
    const float* kj = &qkv[j * 192 + 64];
    float a0 = 0.f, a1 = 0.f, a2 = 0.f, a3 = 0.f;
#pragma unroll
    for (int d = 0; d < 16; ++d) {
      a0 += qi[d] * kj[d];
      a1 += qi[16 + d] * kj[16 + d];
      a2 += qi[32 + d] * kj[32 + d];
      a3 += qi[48 + d] * kj[48 + d];
    }
    a0 *= 0.125f; a1 *= 0.125f; a2 *= 0.125f; a3 *= 0.125f;
    sc[0][j] = a0; sc[1][j] = a1; sc[2][j] = a2; sc[3][j] = a3;
    lm[0] = fmaxf(lm[0], a0); lm[1] = fmaxf(lm[1], a1);
    lm[2] = fmaxf(lm[2], a2); lm[3] = fmaxf(lm[3], a3);
  }
#pragma unroll
  for (int h = 0; h < 4; ++h) {
    float mm = lm[h];
#pragma unroll
    for (int off = 32; off; off >>= 1) mm = fmaxf(mm, __shfl_xor(mm, off));
    if (lane == 0) wred[h][w] = mm;
  }
  __syncthreads();
  if (t < 4)
    hstat[t] = fmaxf(fmaxf(wred[t][0], wred[t][1]), fmaxf(wred[t][2], wred[t][3]));
  __syncthreads();
  const float m0 = hstat[0], m1 = hstat[1], m2 = hstat[2], m3 = hstat[3];
  float ls[4] = {0.f, 0.f, 0.f, 0.f};
  for (int j = t; j < N; j += 256) {
    float p0 = __expf(sc[0][j] - m0), p1 = __expf(sc[1][j] - m1);
    float p2 = __expf(sc[2][j] - m2), p3 = __expf(sc[3][j] - m3);
    sc[0][j] = p0; sc[1][j] = p1; sc[2][j] = p2; sc[3][j] = p3;
    ls[0] += p0; ls[1] += p1; ls[2] += p2; ls[3] += p3;
  }
#pragma unroll
  for (int h = 0; h < 4; ++h) {
    float ss = ls[h];
#pragma unroll
    for (int off = 32; off; off >>= 1) ss += __shfl_xor(ss, off);
    if (lane == 0) wred[h][w] = ss;
  }
  __syncthreads();
  if (t < 4) hstat[4 + t] = wred[t][0] + wred[t][1] + wred[t][2] + wred[t][3];
  __syncthreads();
  const float i0 = 1.f / hstat[4], i1 = 1.f / hstat[5];
  const float i2 = 1.f / hstat[6], i3 = 1.f / hstat[7];
  for (int j = t; j < N; j += 256)
    meanattn[i * N + j] = 0.25f * (sc[0][j] * i0 + sc[1][j] * i1 + sc[2][j] * i2 + sc[3][j] * i3);
  const int hd = lane, h = hd >> 4;
  float acc = 0.f;
  const int j0 = w * 256;
  for (int j = j0; j < j0 + 256; ++j)
    acc += sc[h][j] * qkv[j * 192 + 128 + hd];
  red[t] = acc;
  __syncthreads();
  if (t < 64) {
    const float invh = (t < 16) ? i0 : (t < 32) ? i1 : (t < 48) ? i2 : i3;
    msgv[t] = (red[t] + red[64 + t] + red[128 + t] + red[192 + t]) * invh;
  }
  __syncthreads();
  if (t < 64) {
    float o = out_b[t];
#pragma unroll 8
    for (int k = 0; k < 64; ++k) o += msgv[k] * out_w[k * 64 + t];
    x1[i * D + t] = xn[i * D + t] + o;
  }
}

// ---------------- K3: LN2 + FFN + residual + gate ----------------
__global__ __launch_bounds__(256) void k_ffn_gate(
    const float* __restrict__ x1,
    const float* __restrict__ ln2_g, const float* __restrict__ ln2_b,
    const float* __restrict__ fw1, const float* __restrict__ fb1,
    const float* __restrict__ fw2, const float* __restrict__ fb2,
    const float* __restrict__ gw1, const float* __restrict__ gb1,
    const float* __restrict__ gw2, const float* __restrict__ gb2,
    float* __restrict__ xout, float* __restrict__ gate) {
  const int i = blockIdx.x, t = threadIdx.x;
  __shared__ float xs[64], x1s[64], hs[256];
  if (t < 64) {
    float v = x1[i * 64 + t];
    x1s[t] = v;
    float s = v;
#pragma unroll
    for (int off = 32; off; off >>= 1) s += __shfl_xor(s, off);
    const float m = s * (1.f / 64.f);
    const float dv = v - m;
    float vs = dv * dv;
#pragma unroll
    for (int off = 32; off; off >>= 1) vs += __shfl_xor(vs, off);
    xs[t] = dv * rsqrtf(vs * (1.f / 64.f) + 1e-5f) * ln2_g[t] + ln2_b[t];
  }
  __syncthreads();
  float a = fb1[t];
#pragma unroll 8
  for (int k = 0; k < 64; ++k) a += xs[k] * fw1[k * 256 + t];
  const float ge = 0.5f * a * (1.f + erff(a * 0.70710678118f));
  hs[t] = ge;
  __syncthreads();
  if (t < 64) {
    float o = fb2[t];
#pragma unroll 8
    for (int k = 0; k < 256; ++k) o += hs[k] * fw2[k * 64 + t];
    const float xo = x1s[t] + o;
    xout[i * 64 + t] = xo;
    xs[t] = xo;
  }
  __syncthreads();
  if (t < 64) {
    float a2 = gb1[t];
#pragma unroll 8
    for (int k = 0; k < 64; ++k) a2 += xs[k] * gw1[k * 64 + t];
    const float sg = a2 / (1.f + __expf(-a2));
    float pp = sg * gw2[t];
#pragma unroll
    for (int off = 32; off; off >>= 1) pp += __shfl_xor(pp, off);
    if (t == 0) gate[i] = 1.f / (1.f + __expf(-(pp + gb2[0])));
  }
}

// ---------------- K_prep: pack transposed bf16 weight fragments + fused biases ----------------
// frag f, lane l, elem e. f 0..3 = W1T (row k=9 carries eb1), 4..11 = W2T, 12..19 = C1T
// b3p[d] = cb1[d] + sum_k eb2[k]*cw1[k][d]  (b2 folded through C1)
__global__ __launch_bounds__(256) void k_prep(
    const float* __restrict__ ew1, const float* __restrict__ eb1,
    const float* __restrict__ ew2, const float* __restrict__ cw1,
    const float* __restrict__ eb2, const float* __restrict__ cb1,
    unsigned short* __restrict__ pw, float* __restrict__ b3p) {
  const int t = threadIdx.x;
  for (int idx = t; idx < 20 * 512; idx += 256) {
    const int e = idx & 7, l = (idx >> 3) & 63, f = idx >> 9;
    const int l15 = l & 15, lg = l >> 4;
    float v;
    if (f < 4) {
      const int d = f * 16 + l15, k = lg * 8 + e;
      v = (k < 9) ? ew1[k * 64 + d] : (k == 9 ? eb1[d] : 0.f);
    } else if (f < 12) {
      const int g = f - 4, d = (g >> 1) * 16 + l15, k = (g & 1) * 32 + lg * 8 + e;
      v = ew2[k * 64 + d];
    } else {
      const int g = f - 12, d = (g >> 1) * 16 + l15, k = (g & 1) * 32 + lg * 8 + e;
      v = cw1[k * 64 + d];
    }
    pw[idx] = f2b(v);
  }
  if (t < 64) {
    float s = cb1[t];
#pragma unroll 8
    for (int k = 0; k < 64; ++k) s += eb2[k] * cw1[k * 64 + t];
    b3p[t] = s;
  }
}

// ---------------- K4: MFMA pair pipeline ----------------
// Transposed formulation: M = feature dim (A = weights in VGPRs), N = pair index j.
// LDS: 2 wave-private 32x64 bf16 slots; slot0 = enc then e (aliased), slot1 = h1.
__global__ __launch_bounds__(256, 4) void k_pair(
    const float* __restrict__ coors, const float* __restrict__ meanattn,
    const unsigned short* __restrict__ pw,
    const float* __restrict__ b3p, const float* __restrict__ c2g,
    const float* __restrict__ cb2, const float* __restrict__ gate,
    float* __restrict__ outc) {
  const int i = blockIdx.x;
  const int t = threadIdx.x;
  const int w = t >> 6;
  const int lane = t & 63;
  const int l15 = lane & 15;
  const int lg = lane >> 4;

  __shared__ __align__(16) unsigned short buf[4][2][32][64];
  __shared__ float4 relma[4][32];
  __shared__ float redb[4][3];

  // weight fragments -> registers (80 VGPR)
  bf16x8 wf[20];
#pragma unroll
  for (int f = 0; f < 20; ++f)
    wf[f] = *(const bf16x8*)&pw[(f * 64 + lane) * 8];

  // GEMM3 bias (b2 folded in) + c2, indexed d = mt*16 + lg*4 + r
  float b3v[16], c2v[16];
#pragma unroll
  for (int mt = 0; mt < 4; ++mt)
#pragma unroll
    for (int r = 0; r < 4; ++r) {
      const int d = mt * 16 + lg * 4 + r;
      b3v[mt * 4 + r] = b3p[d];
      c2v[mt * 4 + r] = c2g[d];
    }
  const float cb2q = cb2[0] * 0.25f;
  const float cix = coors[i * 3 + 0], ciy = coors[i * 3 + 1], ciz = coors[i * 3 + 2];

  // one-time zero of enc granules 1..3 (k8..31) so chunk-0 stale LDS can't inject NaN;
  // after chunk 0 these hold finite stale e values multiplied by zero W1T rows.
  if (lane < 32) {
    const int j = lane;
    unsigned short* rp = &buf[w][0][j][0];
    const uint4 z4 = make_uint4(0, 0, 0, 0);
    *(uint4*)&rp[(1 ^ (j & 7)) * 8] = z4;
    *(uint4*)&rp[(2 ^ (j & 7)) * 8] = z4;
    *(uint4*)&rp[(3 ^ (j & 7)) * 8] = z4;
  }

  float dx = 0.f, dy = 0.f, dz = 0.f;
  f32x4 acc[4][2];

  for (int c = 0; c < 8; ++c) {
    // ---- enc + rel*ma (slot0) ----
    if (lane < 32) {
      const int j = lane;
      const int jg = c * 128 + w * 32 + j;
      const float rx = cix - coors[jg * 3 + 0];
      const float ry = ciy - coors[jg * 3 + 1];
      const float rz = ciz - coors[jg * 3 + 2];
      const float rd = rx * rx + ry * ry + rz * rz;
      const float ma = meanattn[i * N + jg];
      relma[w][j] = make_float4(ma * rx, ma * ry, ma * rz, 0.f);
      unsigned short* rp = &buf[w][0][j][0];
      *(uint2*)&rp[(0 ^ (j & 7)) * 8] =
          make_uint2(pk2(__sinf(rd), __sinf(rd * 0.5f)),
                     pk2(__sinf(rd * 0.25f), __sinf(rd * 0.125f)));
      // k8 = rd, k9 = 1.0 (bias row in W1T)
      *(unsigned*)&rp[(1 ^ (j & 7)) * 8] = pk2(rd, 1.0f);
      *(uint2*)&rp[((0 ^ (j & 7)) * 8) + 4] =
          make_uint2(pk2(__cosf(rd), __cosf(rd * 0.5f)),
                     pk2(__cosf(rd * 0.25f), __cosf(rd * 0.125f)));
    }

    // ---- GEMM1: h1T = W1T @ encT  (K=32, bias via k=9) ----
#pragma unroll
    for (int mt = 0; mt < 4; ++mt)
#pragma unroll
      for (int nt = 0; nt < 2; ++nt)
        acc[mt][nt] = (f32x4){0.f, 0.f, 0.f, 0.f};
    {
      const int j0 = l15, j1 = 16 + l15;
      bf16x8 bf0 = *(const bf16x8*)&buf[w][0][j0][(lg ^ (j0 & 7)) * 8];
      bf16x8 bf1 = *(const bf16x8*)&buf[w][0][j1][(lg ^ (j1 & 7)) * 8];
#pragma unroll
      for (int mt = 0; mt < 4; ++mt) {
        acc[mt][0] = __builtin_amdgcn_mfma_f32_16x16x32_bf16(wf[mt], bf0, acc[mt][0], 0, 0, 0);
        acc[mt][1] = __builtin_amdgcn_mfma_f32_16x16x32_bf16(wf[mt], bf1, acc[mt][1], 0, 0, 0);
      }
    }
    // silu -> slot1
#pragma unroll
    for (int mt = 0; mt < 4; ++mt)
#pragma unroll
      for (int nt = 0; nt < 2; ++nt) {
        const f32x4 a = acc[mt][nt];
        const unsigned lo = pk2(silu_f(a[0]), silu_f(a[1]));
        const unsigned hi = pk2(silu_f(a[2]), silu_f(a[3]));
        const int j = nt * 16 + l15;
        const int g = mt * 2 + (lg >> 1);
        *(uint2*)&buf[w][1][j][((g ^ (j & 7)) * 8) + (lg & 1) * 4] = make_uint2(lo, hi);
      }

    // ---- GEMM2: eT = W2T @ h1T  (K=64, bias folded into b3p) ----
#pragma unroll
    for (int mt = 0; mt < 4; ++mt)
#pragma unroll
      for (int nt = 0; nt < 2; ++nt)
        acc[mt][nt] = (f32x4){0.f, 0.f, 0.f, 0.f};
#pragma unroll
    for (int ks = 0; ks < 2; ++ks) {
      const int gi = ks * 4 + lg;
      const int j0 = l15, j1 = 16 + l15;
      bf16x8 bf0 = *(const bf16x8*)&buf[w][1][j0][(gi ^ (j0 & 7)) * 8];
      bf16x8 bf1 = *(const bf16x8*)&buf[w][1][j1][(gi ^ (j1 & 7)) * 8];
#pragma unroll
      for (int mt = 0; mt < 4; ++mt) {
        acc[mt][0] = __builtin_amdgcn_mfma_f32_16x16x32_bf16(wf[4 + mt * 2 + ks], bf0, acc[mt][0], 0, 0, 0);
        acc[mt][1] = __builtin_amdgcn_mfma_f32_16x16x32_bf16(wf[4 + mt * 2 + ks], bf1, acc[mt][1], 0, 0, 0);
      }
    }
    // e (no activation, no bias) -> slot0 (aliases dead enc; per-wave in-order DS)
#pragma unroll
    for (int mt = 0; mt < 4; ++mt)
#pragma unroll
      for (int nt = 0; nt < 2; ++nt) {
        const f32x4 a = acc[mt][nt];
        const unsigned lo = pk2(a[0], a[1]);
        const unsigned hi = pk2(a[2], a[3]);
        const int j = nt * 16 + l15;
        const int g = mt * 2 + (lg >> 1);
        *(uint2*)&buf[w][0][j][((g ^ (j & 7)) * 8) + (lg & 1) * 4] = make_uint2(lo, hi);
      }

    // ---- GEMM3: h2T = C1T @ eT  (K=64) ----
#pragma unroll
    for (int mt = 0; mt < 4; ++mt)
#pragma unroll
      for (int nt = 0; nt < 2; ++nt)
        acc[mt][nt] = (f32x4){b3v[mt * 4 + 0], b3v[mt * 4 + 1], b3v[mt * 4 + 2], b3v[mt * 4 + 3]};
#pragma unroll
    for (int ks = 0; ks < 2; ++ks) {
      const int gi = ks * 4 + lg;
      const int j0 = l15, j1 = 16 + l15;
      bf16x8 bf0 = *(const bf16x8*)&buf[w][0][j0][(gi ^ (j0 & 7)) * 8];
      bf16x8 bf1 = *(const bf16x8*)&buf[w][0][j1][(gi ^ (j1 & 7)) * 8];
#pragma unroll
      for (int mt = 0; mt < 4; ++mt) {
        acc[mt][0] = __builtin_amdgcn_mfma_f32_16x16x32_bf16(wf[12 + mt * 2 + ks], bf0, acc[mt][0], 0, 0, 0);
        acc[mt][1] = __builtin_amdgcn_mfma_f32_16x16x32_bf16(wf[12 + mt * 2 + ks], bf1, acc[mt][1], 0, 0, 0);
      }
    }

    // ---- epilogue: cw partial dot + delta accumulate ----
#pragma unroll
    for (int nt = 0; nt < 2; ++nt) {
      float cwp = cb2q;
#pragma unroll
      for (int mt = 0; mt < 4; ++mt) {
        const f32x4 a = acc[mt][nt];
#pragma unroll
        for (int r = 0; r < 4; ++r) cwp += silu_f(a[r]) * c2v[mt * 4 + r];
      }
      const float4 rm = relma[w][nt * 16 + l15];
      dx += cwp * rm.x;
      dy += cwp * rm.y;
      dz += cwp * rm.z;
    }
  }

  // reduce delta across wave, then block
#pragma unroll
  for (int off = 1; off < 64; off <<= 1) {
    dx += __shfl_xor(dx, off);
    dy += __shfl_xor(dy, off);
    dz += __shfl_xor(dz, off);
  }
  if (lane == 0) { redb[w][0] = dx; redb[w][1] = dy; redb[w][2] = dz; }
  __syncthreads();
  if (t == 0) {
    const float gg = gate[i];
    const float sx = redb[0][0] + redb[1][0] + redb[2][0] + redb[3][0];
    const float sy = redb[0][1] + redb[1][1] + redb[2][1] + redb[3][1];
    const float sz = redb[0][2] + redb[1][2] + redb[2][2] + redb[3][2];
    outc[i * 3 + 0] = cix + sx * gg;
    outc[i * 3 + 1] = ciy + sy * gg;
    outc[i * 3 + 2] = ciz + sz * gg;
  }
}

extern "C" void kernel_launch(void* const* d_in, const int* in_sizes, int n_in,
                              void* d_out, int out_size, void* d_ws, size_t ws_size,
                              hipStream_t stream) {
  const float* feats = (const float*)d_in[0];
  const float* coors = (const float*)d_in[1];
  const float* qkv_w = (const float*)d_in[2];
  const float* out_w = (const float*)d_in[3];
  const float* out_b = (const float*)d_in[4];
  const float* ew1 = (const float*)d_in[5];
  const float* eb1 = (const float*)d_in[6];
  const float* ew2 = (const float*)d_in[7];
  const float* eb2 = (const float*)d_in[8];
  const float* cw1 = (const float*)d_in[9];
  const float* cb1 = (const float*)d_in[10];
  const float* cw2 = (const float*)d_in[11];
  const float* cb2 = (const float*)d_in[12];
  const float* gw1 = (const float*)d_in[13];
  const float* gb1 = (const float*)d_in[14];
  const float* gw2 = (const float*)d_in[15];
  const float* gb2 = (const float*)d_in[16];
  const float* ln1_g = (const float*)d_in[17];
  const float* ln1_b = (const float*)d_in[18];
  const float* ln2_g = (const float*)d_in[19];
  const float* ln2_b = (const float*)d_in[20];
  const float* fw1 = (const float*)d_in[21];
  const float* fb1 = (const float*)d_in[22];
  const float* fw2 = (const float*)d_in[23];
  const float* fb2 = (const float*)d_in[24];

  float* ws = (float*)d_ws;
  float* xn = ws;                         // 65536
  float* qkv = ws + 65536;                // 196608
  float* x1 = ws + 262144;                // 65536
  float* gate = ws + 327680;              // 1024
  unsigned short* pw = (unsigned short*)(ws + 328704);  // 10240 ushort = 5120 floats
  float* b3p = ws + 333824;               // 64
  float* meanattn = ws + 333888;          // 1048576

  float* xout = (float*)d_out;
  float* coorout = xout + 65536;

  hipLaunchKernelGGL(k_ln1_qkv, dim3(N), dim3(64), 0, stream, feats, ln1_g, ln1_b, qkv_w, xn, qkv);
  hipLaunchKernelGGL(k_prep, dim3(1), dim3(256), 0, stream, ew1, eb1, ew2, cw1, eb2, cb1, pw, b3p);
  hipLaunchKernelGGL(k_attn, dim3(N), dim3(256), 0, stream, qkv, xn, out_w, out_b, x1, meanattn);
  hipLaunchKernelGGL(k_ffn_gate, dim3(N), dim3(256), 0, stream, x1, ln2_g, ln2_b,
                     fw1, fb1, fw2, fb2, gw1, gb1, gw2, gb2, xout, gate);
  hipLaunchKernelGGL(k_pair, dim3(N), dim3(256), 0, stream, coors, meanattn, pw,
                     b3p, cw2, cb2, gate, coorout);
}

// Round 4
// 162.124 us; speedup vs baseline: 1.2703x; 1.2703x over previous
//
#include <hip/hip_runtime.h>
#include <hip/hip_bf16.h>

#define N 1024
#define D 64

typedef __attribute__((ext_vector_type(8))) short bf16x8;
typedef __attribute__((ext_vector_type(4))) float f32x4;

__device__ __forceinline__ unsigned short f2b(float v) {
  unsigned u = __float_as_uint(v);
  u += 0x7fffu + ((u >> 16) & 1u);
  return (unsigned short)(u >> 16);
}
// compiler-fusable bf16 pack (emits v_cvt_pk_bf16_f32 for the pair)
__device__ __forceinline__ unsigned pk2(float a, float b) {
  union { __hip_bfloat162 h; unsigned u; } r;
  r.h = __hip_bfloat162(__float2bfloat16(a), __float2bfloat16(b));
  return r.u;
}
__device__ __forceinline__ float silu_f(float x) { return x / (1.f + __expf(-x)); }

// ---------------- K1: LN1 + QKV projection ----------------
__global__ __launch_bounds__(64) void k_ln1_qkv(
    const float* __restrict__ feats, const float* __restrict__ g, const float* __restrict__ b,
    const float* __restrict__ qkv_w, float* __restrict__ xn, float* __restrict__ qkv) {
  const int i = blockIdx.x, t = threadIdx.x;
  float v = feats[i * D + t];
  float s = v;
#pragma unroll
  for (int off = 32; off; off >>= 1) s += __shfl_xor(s, off);
  const float m = s * (1.0f / 64.0f);
  const float dv = v - m;
  float vs = dv * dv;
#pragma unroll
  for (int off = 32; off; off >>= 1) vs += __shfl_xor(vs, off);
  const float var = vs * (1.0f / 64.0f);
  const float xv = dv * rsqrtf(var + 1e-5f) * g[t] + b[t];
  xn[i * D + t] = xv;
  __shared__ float xs[D];
  xs[t] = xv;
  __syncthreads();
#pragma unroll
  for (int c = 0; c < 3; ++c) {
    const int col = t + c * 64;
    float acc = 0.f;
#pragma unroll 8
    for (int k = 0; k < D; ++k) acc += xs[k] * qkv_w[k * 192 + col];
    qkv[i * 192 + col] = acc;
  }
}

// ---------------- K2: attention + mean-attn + out-proj + residual ----------------
__global__ __launch_bounds__(256) void k_attn(
    const float* __restrict__ qkv, const float* __restrict__ xn,
    const float* __restrict__ out_w, const float* __restrict__ out_b,
    float* __restrict__ x1, float* __restrict__ meanattn) {
  const int i = blockIdx.x, t = threadIdx.x;
  const int lane = t & 63, w = t >> 6;
  __shared__ float sc[4][N];
  __shared__ float qi[D];
  __shared__ float wred[4][4];
  __shared__ float hstat[8];
  __shared__ float red[256];
  __shared__ float msgv[64];
  if (t < D) qi[t] = qkv[i * 192 + t];
  __syncthreads();
  float lm[4] = {-1e30f, -1e30f, -1e30f, -1e30f};
  for (int j = t; j < N; j += 256) {
    const float* kj = &qkv[j * 192 + 64];
    float a0 = 0.f, a1 = 0.f, a2 = 0.f, a3 = 0.f;
#pragma unroll
    for (int d = 0; d < 16; ++d) {
      a0 += qi[d] * kj[d];
      a1 += qi[16 + d] * kj[16 + d];
      a2 += qi[32 + d] * kj[32 + d];
      a3 += qi[48 + d] * kj[48 + d];
    }
    a0 *= 0.125f; a1 *= 0.125f; a2 *= 0.125f; a3 *= 0.125f;
    sc[0][j] = a0; sc[1][j] = a1; sc[2][j] = a2; sc[3][j] = a3;
    lm[0] = fmaxf(lm[0], a0); lm[1] = fmaxf(lm[1], a1);
    lm[2] = fmaxf(lm[2], a2); lm[3] = fmaxf(lm[3], a3);
  }
#pragma unroll
  for (int h = 0; h < 4; ++h) {
    float mm = lm[h];
#pragma unroll
    for (int off = 32; off; off >>= 1) mm = fmaxf(mm, __shfl_xor(mm, off));
    if (lane == 0) wred[h][w] = mm;
  }
  __syncthreads();
  if (t < 4)
    hstat[t] = fmaxf(fmaxf(wred[t][0], wred[t][1]), fmaxf(wred[t][2], wred[t][3]));
  __syncthreads();
  const float m0 = hstat[0], m1 = hstat[1], m2 = hstat[2], m3 = hstat[3];
  float ls[4] = {0.f, 0.f, 0.f, 0.f};
  for (int j = t; j < N; j += 256) {
    float p0 = __expf(sc[0][j] - m0), p1 = __expf(sc[1][j] - m1);
    float p2 = __expf(sc[2][j] - m2), p3 = __expf(sc[3][j] - m3);
    sc[0][j] = p0; sc[1][j] = p1; sc[2][j] = p2; sc[3][j] = p3;
    ls[0] += p0; ls[1] += p1; ls[2] += p2; ls[3] += p3;
  }
#pragma unroll
  for (int h = 0; h < 4; ++h) {
    float ss = ls[h];
#pragma unroll
    for (int off = 32; off; off >>= 1) ss += __shfl_xor(ss, off);
    if (lane == 0) wred[h][w] = ss;
  }
  __syncthreads();
  if (t < 4) hstat[4 + t] = wred[t][0] + wred[t][1] + wred[t][2] + wred[t][3];
  __syncthreads();
  const float i0 = 1.f / hstat[4], i1 = 1.f / hstat[5];
  const float i2 = 1.f / hstat[6], i3 = 1.f / hstat[7];
  for (int j = t; j < N; j += 256)
    meanattn[i * N + j] = 0.25f * (sc[0][j] * i0 + sc[1][j] * i1 + sc[2][j] * i2 + sc[3][j] * i3);
  const int hd = lane, h = hd >> 4;
  float acc = 0.f;
  const int j0 = w * 256;
  for (int j = j0; j < j0 + 256; ++j)
    acc += sc[h][j] * qkv[j * 192 + 128 + hd];
  red[t] = acc;
  __syncthreads();
  if (t < 64) {
    const float invh = (t < 16) ? i0 : (t < 32) ? i1 : (t < 48) ? i2 : i3;
    msgv[t] = (red[t] + red[64 + t] + red[128 + t] + red[192 + t]) * invh;
  }
  __syncthreads();
  if (t < 64) {
    float o = out_b[t];
#pragma unroll 8
    for (int k = 0; k < 64; ++k) o += msgv[k] * out_w[k * 64 + t];
    x1[i * D + t] = xn[i * D + t] + o;
  }
}

// ---------------- K3: LN2 + FFN + residual + gate ----------------
__global__ __launch_bounds__(256) void k_ffn_gate(
    const float* __restrict__ x1,
    const float* __restrict__ ln2_g, const float* __restrict__ ln2_b,
    const float* __restrict__ fw1, const float* __restrict__ fb1,
    const float* __restrict__ fw2, const float* __restrict__ fb2,
    const float* __restrict__ gw1, const float* __restrict__ gb1,
    const float* __restrict__ gw2, const float* __restrict__ gb2,
    float* __restrict__ xout, float* __restrict__ gate) {
  const int i = blockIdx.x, t = threadIdx.x;
  __shared__ float xs[64], x1s[64], hs[256];
  if (t < 64) {
    float v = x1[i * 64 + t];
    x1s[t] = v;
    float s = v;
#pragma unroll
    for (int off = 32; off; off >>= 1) s += __shfl_xor(s, off);
    const float m = s * (1.f / 64.f);
    const float dv = v - m;
    float vs = dv * dv;
#pragma unroll
    for (int off = 32; off; off >>= 1) vs += __shfl_xor(vs, off);
    xs[t] = dv * rsqrtf(vs * (1.f / 64.f) + 1e-5f) * ln2_g[t] + ln2_b[t];
  }
  __syncthreads();
  float a = fb1[t];
#pragma unroll 8
  for (int k = 0; k < 64; ++k) a += xs[k] * fw1[k * 256 + t];
  const float ge = 0.5f * a * (1.f + erff(a * 0.70710678118f));
  hs[t] = ge;
  __syncthreads();
  if (t < 64) {
    float o = fb2[t];
#pragma unroll 8
    for (int k = 0; k < 256; ++k) o += hs[k] * fw2[k * 64 + t];
    const float xo = x1s[t] + o;
    xout[i * 64 + t] = xo;
    xs[t] = xo;
  }
  __syncthreads();
  if (t < 64) {
    float a2 = gb1[t];
#pragma unroll 8
    for (int k = 0; k < 64; ++k) a2 += xs[k] * gw1[k * 64 + t];
    const float sg = a2 / (1.f + __expf(-a2));
    float pp = sg * gw2[t];
#pragma unroll
    for (int off = 32; off; off >>= 1) pp += __shfl_xor(pp, off);
    if (t == 0) gate[i] = 1.f / (1.f + __expf(-(pp + gb2[0])));
  }
}

// ---------------- K_prep: pack transposed bf16 weight fragments + fused biases ----------------
// frag f, lane l, elem e. f 0..3 = W1T (row k=9 carries eb1), 4..11 = W2T, 12..19 = C1T
// b3p[d] = cb1[d] + sum_k eb2[k]*cw1[k][d]  (b2 folded through C1)
__global__ __launch_bounds__(256) void k_prep(
    const float* __restrict__ ew1, const float* __restrict__ eb1,
    const float* __restrict__ ew2, const float* __restrict__ cw1,
    const float* __restrict__ eb2, const float* __restrict__ cb1,
    unsigned short* __restrict__ pw, float* __restrict__ b3p) {
  const int t = threadIdx.x;
  for (int idx = t; idx < 20 * 512; idx += 256) {
    const int e = idx & 7, l = (idx >> 3) & 63, f = idx >> 9;
    const int l15 = l & 15, lg = l >> 4;
    float v;
    if (f < 4) {
      const int d = f * 16 + l15, k = lg * 8 + e;
      v = (k < 9) ? ew1[k * 64 + d] : (k == 9 ? eb1[d] : 0.f);
    } else if (f < 12) {
      const int g = f - 4, d = (g >> 1) * 16 + l15, k = (g & 1) * 32 + lg * 8 + e;
      v = ew2[k * 64 + d];
    } else {
      const int g = f - 12, d = (g >> 1) * 16 + l15, k = (g & 1) * 32 + lg * 8 + e;
      v = cw1[k * 64 + d];
    }
    pw[idx] = f2b(v);
  }
  if (t < 64) {
    float s = cb1[t];
#pragma unroll 8
    for (int k = 0; k < 64; ++k) s += eb2[k] * cw1[k * 64 + t];
    b3p[t] = s;
  }
}

// ---------------- K4: MFMA pair pipeline ----------------
// Transposed formulation: M = feature dim (A = weights in VGPRs), N = pair index j.
// LDS: 2 wave-private 32x64 bf16 slots; slot0 = enc then e (aliased), slot1 = h1.
// launch_bounds (256,2): R3's (256,4) capped VGPR at 128 < live demand -> catastrophic
// scratch spill (FETCH 234MB). (256,2) proven (R2): ~116 VGPR, no spill; LDS 35KB
// still allows 4 blocks/CU if the allocator lands <=128.
__global__ __launch_bounds__(256, 2) void k_pair(
    const float* __restrict__ coors, const float* __restrict__ meanattn,
    const unsigned short* __restrict__ pw,
    const float* __restrict__ b3p, const float* __restrict__ c2g,
    const float* __restrict__ cb2, const float* __restrict__ gate,
    float* __restrict__ outc) {
  const int i = blockIdx.x;
  const int t = threadIdx.x;
  const int w = t >> 6;
  const int lane = t & 63;
  const int l15 = lane & 15;
  const int lg = lane >> 4;

  __shared__ __align__(16) unsigned short buf[4][2][32][64];
  __shared__ float4 relma[4][32];
  __shared__ float redb[4][3];

  // weight fragments -> registers (80 VGPR)
  bf16x8 wf[20];
#pragma unroll
  for (int f = 0; f < 20; ++f)
    wf[f] = *(const bf16x8*)&pw[(f * 64 + lane) * 8];

  // GEMM3 bias (b2 folded in) + c2, indexed d = mt*16 + lg*4 + r
  float b3v[16], c2v[16];
#pragma unroll
  for (int mt = 0; mt < 4; ++mt)
#pragma unroll
    for (int r = 0; r < 4; ++r) {
      const int d = mt * 16 + lg * 4 + r;
      b3v[mt * 4 + r] = b3p[d];
      c2v[mt * 4 + r] = c2g[d];
    }
  const float cb2q = cb2[0] * 0.25f;
  const float cix = coors[i * 3 + 0], ciy = coors[i * 3 + 1], ciz = coors[i * 3 + 2];

  // one-time zero of enc granules 1..3 (k8..31) so chunk-0 stale LDS can't inject NaN;
  // after chunk 0 these hold finite stale e values multiplied by zero W1T rows.
  if (lane < 32) {
    const int j = lane;
    unsigned short* rp = &buf[w][0][j][0];
    const uint4 z4 = make_uint4(0, 0, 0, 0);
    *(uint4*)&rp[(1 ^ (j & 7)) * 8] = z4;
    *(uint4*)&rp[(2 ^ (j & 7)) * 8] = z4;
    *(uint4*)&rp[(3 ^ (j & 7)) * 8] = z4;
  }

  float dx = 0.f, dy = 0.f, dz = 0.f;
  f32x4 acc[4][2];

  for (int c = 0; c < 8; ++c) {
    // ---- enc + rel*ma (slot0) ----
    if (lane < 32) {
      const int j = lane;
      const int jg = c * 128 + w * 32 + j;
      const float rx = cix - coors[jg * 3 + 0];
      const float ry = ciy - coors[jg * 3 + 1];
      const float rz = ciz - coors[jg * 3 + 2];
      const float rd = rx * rx + ry * ry + rz * rz;
      const float ma = meanattn[i * N + jg];
      relma[w][j] = make_float4(ma * rx, ma * ry, ma * rz, 0.f);
      unsigned short* rp = &buf[w][0][j][0];
      *(uint2*)&rp[(0 ^ (j & 7)) * 8] =
          make_uint2(pk2(__sinf(rd), __sinf(rd * 0.5f)),
                     pk2(__sinf(rd * 0.25f), __sinf(rd * 0.125f)));
      // k8 = rd, k9 = 1.0 (bias row in W1T)
      *(unsigned*)&rp[(1 ^ (j & 7)) * 8] = pk2(rd, 1.0f);
      *(uint2*)&rp[((0 ^ (j & 7)) * 8) + 4] =
          make_uint2(pk2(__cosf(rd), __cosf(rd * 0.5f)),
                     pk2(__cosf(rd * 0.25f), __cosf(rd * 0.125f)));
    }

    // ---- GEMM1: h1T = W1T @ encT  (K=32, bias via k=9) ----
#pragma unroll
    for (int mt = 0; mt < 4; ++mt)
#pragma unroll
      for (int nt = 0; nt < 2; ++nt)
        acc[mt][nt] = (f32x4){0.f, 0.f, 0.f, 0.f};
    {
      const int j0 = l15, j1 = 16 + l15;
      bf16x8 bf0 = *(const bf16x8*)&buf[w][0][j0][(lg ^ (j0 & 7)) * 8];
      bf16x8 bf1 = *(const bf16x8*)&buf[w][0][j1][(lg ^ (j1 & 7)) * 8];
#pragma unroll
      for (int mt = 0; mt < 4; ++mt) {
        acc[mt][0] = __builtin_amdgcn_mfma_f32_16x16x32_bf16(wf[mt], bf0, acc[mt][0], 0, 0, 0);
        acc[mt][1] = __builtin_amdgcn_mfma_f32_16x16x32_bf16(wf[mt], bf1, acc[mt][1], 0, 0, 0);
      }
    }
    // silu -> slot1
#pragma unroll
    for (int mt = 0; mt < 4; ++mt)
#pragma unroll
      for (int nt = 0; nt < 2; ++nt) {
        const f32x4 a = acc[mt][nt];
        const unsigned lo = pk2(silu_f(a[0]), silu_f(a[1]));
        const unsigned hi = pk2(silu_f(a[2]), silu_f(a[3]));
        const int j = nt * 16 + l15;
        const int g = mt * 2 + (lg >> 1);
        *(uint2*)&buf[w][1][j][((g ^ (j & 7)) * 8) + (lg & 1) * 4] = make_uint2(lo, hi);
      }

    // ---- GEMM2: eT = W2T @ h1T  (K=64, bias folded into b3p) ----
#pragma unroll
    for (int mt = 0; mt < 4; ++mt)
#pragma unroll
      for (int nt = 0; nt < 2; ++nt)
        acc[mt][nt] = (f32x4){0.f, 0.f, 0.f, 0.f};
#pragma unroll
    for (int ks = 0; ks < 2; ++ks) {
      const int gi = ks * 4 + lg;
      const int j0 = l15, j1 = 16 + l15;
      bf16x8 bf0 = *(const bf16x8*)&buf[w][1][j0][(gi ^ (j0 & 7)) * 8];
      bf16x8 bf1 = *(const bf16x8*)&buf[w][1][j1][(gi ^ (j1 & 7)) * 8];
#pragma unroll
      for (int mt = 0; mt < 4; ++mt) {
        acc[mt][0] = __builtin_amdgcn_mfma_f32_16x16x32_bf16(wf[4 + mt * 2 + ks], bf0, acc[mt][0], 0, 0, 0);
        acc[mt][1] = __builtin_amdgcn_mfma_f32_16x16x32_bf16(wf[4 + mt * 2 + ks], bf1, acc[mt][1], 0, 0, 0);
      }
    }
    // e (no activation, no bias) -> slot0 (aliases dead enc; per-wave in-order DS)
#pragma unroll
    for (int mt = 0; mt < 4; ++mt)
#pragma unroll
      for (int nt = 0; nt < 2; ++nt) {
        const f32x4 a = acc[mt][nt];
        const unsigned lo = pk2(a[0], a[1]);
        const unsigned hi = pk2(a[2], a[3]);
        const int j = nt * 16 + l15;
        const int g = mt * 2 + (lg >> 1);
        *(uint2*)&buf[w][0][j][((g ^ (j & 7)) * 8) + (lg & 1) * 4] = make_uint2(lo, hi);
      }

    // ---- GEMM3: h2T = C1T @ eT  (K=64) ----
#pragma unroll
    for (int mt = 0; mt < 4; ++mt)
#pragma unroll
      for (int nt = 0; nt < 2; ++nt)
        acc[mt][nt] = (f32x4){b3v[mt * 4 + 0], b3v[mt * 4 + 1], b3v[mt * 4 + 2], b3v[mt * 4 + 3]};
#pragma unroll
    for (int ks = 0; ks < 2; ++ks) {
      const int gi = ks * 4 + lg;
      const int j0 = l15, j1 = 16 + l15;
      bf16x8 bf0 = *(const bf16x8*)&buf[w][0][j0][(gi ^ (j0 & 7)) * 8];
      bf16x8 bf1 = *(const bf16x8*)&buf[w][0][j1][(gi ^ (j1 & 7)) * 8];
#pragma unroll
      for (int mt = 0; mt < 4; ++mt) {
        acc[mt][0] = __builtin_amdgcn_mfma_f32_16x16x32_bf16(wf[12 + mt * 2 + ks], bf0, acc[mt][0], 0, 0, 0);
        acc[mt][1] = __builtin_amdgcn_mfma_f32_16x16x32_bf16(wf[12 + mt * 2 + ks], bf1, acc[mt][1], 0, 0, 0);
      }
    }

    // ---- epilogue: cw partial dot + delta accumulate ----
#pragma unroll
    for (int nt = 0; nt < 2; ++nt) {
      float cwp = cb2q;
#pragma unroll
      for (int mt = 0; mt < 4; ++mt) {
        const f32x4 a = acc[mt][nt];
#pragma unroll
        for (int r = 0; r < 4; ++r) cwp += silu_f(a[r]) * c2v[mt * 4 + r];
      }
      const float4 rm = relma[w][nt * 16 + l15];
      dx += cwp * rm.x;
      dy += cwp * rm.y;
      dz += cwp * rm.z;
    }
  }

  // reduce delta across wave, then block
#pragma unroll
  for (int off = 1; off < 64; off <<= 1) {
    dx += __shfl_xor(dx, off);
    dy += __shfl_xor(dy, off);
    dz += __shfl_xor(dz, off);
  }
  if (lane == 0) { redb[w][0] = dx; redb[w][1] = dy; redb[w][2] = dz; }
  __syncthreads();
  if (t == 0) {
    const float gg = gate[i];
    const float sx = redb[0][0] + redb[1][0] + redb[2][0] + redb[3][0];
    const float sy = redb[0][1] + redb[1][1] + redb[2][1] + redb[3][1];
    const float sz = redb[0][2] + redb[1][2] + redb[2][2] + redb[3][2];
    outc[i * 3 + 0] = cix + sx * gg;
    outc[i * 3 + 1] = ciy + sy * gg;
    outc[i * 3 + 2] = ciz + sz * gg;
  }
}

extern "C" void kernel_launch(void* const* d_in, const int* in_sizes, int n_in,
                              void* d_out, int out_size, void* d_ws, size_t ws_size,
                              hipStream_t stream) {
  const float* feats = (const float*)d_in[0];
  const float* coors = (const float*)d_in[1];
  const float* qkv_w = (const float*)d_in[2];
  const float* out_w = (const float*)d_in[3];
  const float* out_b = (const float*)d_in[4];
  const float* ew1 = (const float*)d_in[5];
  const float* eb1 = (const float*)d_in[6];
  const float* ew2 = (const float*)d_in[7];
  const float* eb2 = (const float*)d_in[8];
  const float* cw1 = (const float*)d_in[9];
  const float* cb1 = (const float*)d_in[10];
  const float* cw2 = (const float*)d_in[11];
  const float* cb2 = (const float*)d_in[12];
  const float* gw1 = (const float*)d_in[13];
  const float* gb1 = (const float*)d_in[14];
  const float* gw2 = (const float*)d_in[15];
  const float* gb2 = (const float*)d_in[16];
  const float* ln1_g = (const float*)d_in[17];
  const float* ln1_b = (const float*)d_in[18];
  const float* ln2_g = (const float*)d_in[19];
  const float* ln2_b = (const float*)d_in[20];
  const float* fw1 = (const float*)d_in[21];
  const float* fb1 = (const float*)d_in[22];
  const float* fw2 = (const float*)d_in[23];
  const float* fb2 = (const float*)d_in[24];

  float* ws = (float*)d_ws;
  float* xn = ws;                         // 65536
  float* qkv = ws + 65536;                // 196608
  float* x1 = ws + 262144;                // 65536
  float* gate = ws + 327680;              // 1024
  unsigned short* pw = (unsigned short*)(ws + 328704);  // 10240 ushort = 5120 floats
  float* b3p = ws + 333824;               // 64
  float* meanattn = ws + 333888;          // 1048576

  float* xout = (float*)d_out;
  float* coorout = xout + 65536;

  hipLaunchKernelGGL(k_ln1_qkv, dim3(N), dim3(64), 0, stream, feats, ln1_g, ln1_b, qkv_w, xn, qkv);
  hipLaunchKernelGGL(k_prep, dim3(1), dim3(256), 0, stream, ew1, eb1, ew2, cw1, eb2, cb1, pw, b3p);
  hipLaunchKernelGGL(k_attn, dim3(N), dim3(256), 0, stream, qkv, xn, out_w, out_b, x1, meanattn);
  hipLaunchKernelGGL(k_ffn_gate, dim3(N), dim3(256), 0, stream, x1, ln2_g, ln2_b,
                     fw1, fb1, fw2, fb2, gw1, gb1, gw2, gb2, xout, gate);
  hipLaunchKernelGGL(k_pair, dim3(N), dim3(256), 0, stream, coors, meanattn, pw,
                     b3p, cw2, cb2, gate, coorout);
}

// Round 5
// 136.643 us; speedup vs baseline: 1.5072x; 1.1865x over previous
//
#include <hip/hip_runtime.h>
#include <hip/hip_bf16.h>

#define N 1024
#define D 64

typedef __attribute__((ext_vector_type(8))) short bf16x8;
typedef __attribute__((ext_vector_type(4))) float f32x4;

__device__ __forceinline__ unsigned short f2b(float v) {
  unsigned u = __float_as_uint(v);
  u += 0x7fffu + ((u >> 16) & 1u);
  return (unsigned short)(u >> 16);
}
// compiler-fusable bf16 pack (emits v_cvt_pk_bf16_f32 for the pair)
__device__ __forceinline__ unsigned pk2(float a, float b) {
  union { __hip_bfloat162 h; unsigned u; } r;
  r.h = __hip_bfloat162(__float2bfloat16(a), __float2bfloat16(b));
  return r.u;
}
// fast silu: x * rcp(1+exp(-x)) — v_rcp_f32 (~1ulp) instead of IEEE divide (~9 inst)
__device__ __forceinline__ float silu_f(float x) {
  return x * __builtin_amdgcn_rcpf(1.f + __expf(-x));
}
__device__ __forceinline__ float sigm_f(float x) {
  return __builtin_amdgcn_rcpf(1.f + __expf(-x));
}

// ---------------- K1: LN1 + QKV projection ----------------
__global__ __launch_bounds__(64) void k_ln1_qkv(
    const float* __restrict__ feats, const float* __restrict__ g, const float* __restrict__ b,
    const float* __restrict__ qkv_w, float* __restrict__ xn, float* __restrict__ qkv) {
  const int i = blockIdx.x, t = threadIdx.x;
  float v = feats[i * D + t];
  float s = v;
#pragma unroll
  for (int off = 32; off; off >>= 1) s += __shfl_xor(s, off);
  const float m = s * (1.0f / 64.0f);
  const float dv = v - m;
  float vs = dv * dv;
#pragma unroll
  for (int off = 32; off; off >>= 1) vs += __shfl_xor(vs, off);
  const float var = vs * (1.0f / 64.0f);
  const float xv = dv * rsqrtf(var + 1e-5f) * g[t] + b[t];
  xn[i * D + t] = xv;
  __shared__ float xs[D];
  xs[t] = xv;
  __syncthreads();
#pragma unroll
  for (int c = 0; c < 3; ++c) {
    const int col = t + c * 64;
    float acc = 0.f;
#pragma unroll 8
    for (int k = 0; k < D; ++k) acc += xs[k] * qkv_w[k * 192 + col];
    qkv[i * 192 + col] = acc;
  }
}

// ---------------- K2: attention + mean-attn + out-proj + residual ----------------
__global__ __launch_bounds__(256) void k_attn(
    const float* __restrict__ qkv, const float* __restrict__ xn,
    const float* __restrict__ out_w, const float* __restrict__ out_b,
    float* __restrict__ x1, float* __restrict__ meanattn) {
  const int i = blockIdx.x, t = threadIdx.x;
  const int lane = t & 63, w = t >> 6;
  __shared__ float sc[4][N];
  __shared__ float qi[D];
  __shared__ float wred[4][4];
  __shared__ float hstat[8];
  __shared__ float red[256];
  __shared__ float msgv[64];
  if (t < D) qi[t] = qkv[i * 192 + t];
  __syncthreads();
  float lm[4] = {-1e30f, -1e30f, -1e30f, -1e30f};
  for (int j = t; j < N; j += 256) {
    const float* kj = &qkv[j * 192 + 64];
    float a0 = 0.f, a1 = 0.f, a2 = 0.f, a3 = 0.f;
#pragma unroll
    for (int d = 0; d < 16; ++d) {
      a0 += qi[d] * kj[d];
      a1 += qi[16 + d] * kj[16 + d];
      a2 += qi[32 + d] * kj[32 + d];
      a3 += qi[48 + d] * kj[48 + d];
    }
    a0 *= 0.125f; a1 *= 0.125f; a2 *= 0.125f; a3 *= 0.125f;
    sc[0][j] = a0; sc[1][j] = a1; sc[2][j] = a2; sc[3][j] = a3;
    lm[0] = fmaxf(lm[0], a0); lm[1] = fmaxf(lm[1], a1);
    lm[2] = fmaxf(lm[2], a2); lm[3] = fmaxf(lm[3], a3);
  }
#pragma unroll
  for (int h = 0; h < 4; ++h) {
    float mm = lm[h];
#pragma unroll
    for (int off = 32; off; off >>= 1) mm = fmaxf(mm, __shfl_xor(mm, off));
    if (lane == 0) wred[h][w] = mm;
  }
  __syncthreads();
  if (t < 4)
    hstat[t] = fmaxf(fmaxf(wred[t][0], wred[t][1]), fmaxf(wred[t][2], wred[t][3]));
  __syncthreads();
  const float m0 = hstat[0], m1 = hstat[1], m2 = hstat[2], m3 = hstat[3];
  float ls[4] = {0.f, 0.f, 0.f, 0.f};
  for (int j = t; j < N; j += 256) {
    float p0 = __expf(sc[0][j] - m0), p1 = __expf(sc[1][j] - m1);
    float p2 = __expf(sc[2][j] - m2), p3 = __expf(sc[3][j] - m3);
    sc[0][j] = p0; sc[1][j] = p1; sc[2][j] = p2; sc[3][j] = p3;
    ls[0] += p0; ls[1] += p1; ls[2] += p2; ls[3] += p3;
  }
#pragma unroll
  for (int h = 0; h < 4; ++h) {
    float ss = ls[h];
#pragma unroll
    for (int off = 32; off; off >>= 1) ss += __shfl_xor(ss, off);
    if (lane == 0) wred[h][w] = ss;
  }
  __syncthreads();
  if (t < 4) hstat[4 + t] = wred[t][0] + wred[t][1] + wred[t][2] + wred[t][3];
  __syncthreads();
  const float i0 = __builtin_amdgcn_rcpf(hstat[4]);
  const float i1 = __builtin_amdgcn_rcpf(hstat[5]);
  const float i2 = __builtin_amdgcn_rcpf(hstat[6]);
  const float i3 = __builtin_amdgcn_rcpf(hstat[7]);
  for (int j = t; j < N; j += 256)
    meanattn[i * N + j] = 0.25f * (sc[0][j] * i0 + sc[1][j] * i1 + sc[2][j] * i2 + sc[3][j] * i3);
  const int hd = lane, h = hd >> 4;
  float acc = 0.f;
  const int j0 = w * 256;
  for (int j = j0; j < j0 + 256; ++j)
    acc += sc[h][j] * qkv[j * 192 + 128 + hd];
  red[t] = acc;
  __syncthreads();
  if (t < 64) {
    const float invh = (t < 16) ? i0 : (t < 32) ? i1 : (t < 48) ? i2 : i3;
    msgv[t] = (red[t] + red[64 + t] + red[128 + t] + red[192 + t]) * invh;
  }
  __syncthreads();
  if (t < 64) {
    float o = out_b[t];
#pragma unroll 8
    for (int k = 0; k < 64; ++k) o += msgv[k] * out_w[k * 64 + t];
    x1[i * D + t] = xn[i * D + t] + o;
  }
}

// ---------------- K3: LN2 + FFN + residual + gate ----------------
__global__ __launch_bounds__(256) void k_ffn_gate(
    const float* __restrict__ x1,
    const float* __restrict__ ln2_g, const float* __restrict__ ln2_b,
    const float* __restrict__ fw1, const float* __restrict__ fb1,
    const float* __restrict__ fw2, const float* __restrict__ fb2,
    const float* __restrict__ gw1, const float* __restrict__ gb1,
    const float* __restrict__ gw2, const float* __restrict__ gb2,
    float* __restrict__ xout, float* __restrict__ gate) {
  const int i = blockIdx.x, t = threadIdx.x;
  __shared__ float xs[64], x1s[64], hs[256];
  if (t < 64) {
    float v = x1[i * 64 + t];
    x1s[t] = v;
    float s = v;
#pragma unroll
    for (int off = 32; off; off >>= 1) s += __shfl_xor(s, off);
    const float m = s * (1.f / 64.f);
    const float dv = v - m;
    float vs = dv * dv;
#pragma unroll
    for (int off = 32; off; off >>= 1) vs += __shfl_xor(vs, off);
    xs[t] = dv * rsqrtf(vs * (1.f / 64.f) + 1e-5f) * ln2_g[t] + ln2_b[t];
  }
  __syncthreads();
  float a = fb1[t];
#pragma unroll 8
  for (int k = 0; k < 64; ++k) a += xs[k] * fw1[k * 256 + t];
  const float ge = 0.5f * a * (1.f + erff(a * 0.70710678118f));
  hs[t] = ge;
  __syncthreads();
  if (t < 64) {
    float o = fb2[t];
#pragma unroll 8
    for (int k = 0; k < 256; ++k) o += hs[k] * fw2[k * 64 + t];
    const float xo = x1s[t] + o;
    xout[i * 64 + t] = xo;
    xs[t] = xo;
  }
  __syncthreads();
  if (t < 64) {
    float a2 = gb1[t];
#pragma unroll 8
    for (int k = 0; k < 64; ++k) a2 += xs[k] * gw1[k * 64 + t];
    const float sg = a2 * sigm_f(a2);
    float pp = sg * gw2[t];
#pragma unroll
    for (int off = 32; off; off >>= 1) pp += __shfl_xor(pp, off);
    if (t == 0) gate[i] = sigm_f(pp + gb2[0]);
  }
}

// ---------------- K_prep: fold W2@C1, pack bf16 A-fragments + fused bias ----------------
// GEMM2+GEMM3 merged: h2 = (W2@C1)^T h1 + b3,  b3 = cb1 + C1^T eb2.
// frags f 0..3 = W1T (row k=9 carries eb1), f 4..11 = Wc^T (Wc = ew2@cw1).
__global__ __launch_bounds__(256) void k_prep(
    const float* __restrict__ ew1, const float* __restrict__ eb1,
    const float* __restrict__ ew2, const float* __restrict__ cw1,
    const float* __restrict__ eb2, const float* __restrict__ cb1,
    unsigned short* __restrict__ pw, float* __restrict__ b3p) {
  const int t = threadIdx.x;
  __shared__ float wc[64][64];
  for (int idx = t; idx < 4096; idx += 256) {
    const int r = idx >> 6, c = idx & 63;
    float s = 0.f;
#pragma unroll 8
    for (int k = 0; k < 64; ++k) s += ew2[r * 64 + k] * cw1[k * 64 + c];
    wc[r][c] = s;
  }
  __syncthreads();
  for (int idx = t; idx < 12 * 512; idx += 256) {
    const int e = idx & 7, l = (idx >> 3) & 63, f = idx >> 9;
    const int l15 = l & 15, lg = l >> 4;
    float v;
    if (f < 4) {
      const int d = f * 16 + l15, k = lg * 8 + e;
      v = (k < 9) ? ew1[k * 64 + d] : (k == 9 ? eb1[d] : 0.f);
    } else {
      const int g = f - 4, d = (g >> 1) * 16 + l15, k = (g & 1) * 32 + lg * 8 + e;
      v = wc[k][d];
    }
    pw[idx] = f2b(v);
  }
  if (t < 64) {
    float s = cb1[t];
#pragma unroll 8
    for (int k = 0; k < 64; ++k) s += eb2[k] * cw1[k * 64 + t];
    b3p[t] = s;
  }
}

// ---------------- K4: MFMA pair pipeline (2 chained GEMMs) ----------------
// M = feature dim (A = weights in VGPRs), N = pair index j. Per wave: 32-j panel.
// slot0 = enc (K=32 padded, persistent zeros k>=10), slot1 = h1.
__global__ __launch_bounds__(256, 2) void k_pair(
    const float* __restrict__ coors, const float* __restrict__ meanattn,
    const unsigned short* __restrict__ pw,
    const float* __restrict__ b3p, const float* __restrict__ c2g,
    const float* __restrict__ cb2, const float* __restrict__ gate,
    float* __restrict__ outc) {
  const int i = blockIdx.x;
  const int t = threadIdx.x;
  const int w = t >> 6;
  const int lane = t & 63;
  const int l15 = lane & 15;
  const int lg = lane >> 4;

  __shared__ __align__(16) unsigned short buf[4][2][32][64];
  __shared__ float4 relma[4][32];
  __shared__ float redb[4][3];

  // weight fragments -> registers (48 VGPR)
  bf16x8 wf[12];
#pragma unroll
  for (int f = 0; f < 12; ++f)
    wf[f] = *(const bf16x8*)&pw[(f * 64 + lane) * 8];

  // merged-GEMM bias + c2, indexed d = mt*16 + lg*4 + r
  float b3v[16], c2v[16];
#pragma unroll
  for (int mt = 0; mt < 4; ++mt)
#pragma unroll
    for (int r = 0; r < 4; ++r) {
      const int d = mt * 16 + lg * 4 + r;
      b3v[mt * 4 + r] = b3p[d];
      c2v[mt * 4 + r] = c2g[d];
    }
  const float cb2q = cb2[0] * 0.25f;
  const float cix = coors[i * 3 + 0], ciy = coors[i * 3 + 1], ciz = coors[i * 3 + 2];

  // one-time zero of enc logical granules 1..3 (k8..31); k8,k9 rewritten per chunk,
  // k10..31 stay zero for the whole kernel (slot0 is no longer aliased).
  if (lane < 32) {
    const int j = lane;
    unsigned short* rp = &buf[w][0][j][0];
    const uint4 z4 = make_uint4(0, 0, 0, 0);
    *(uint4*)&rp[(1 ^ (j & 7)) * 8] = z4;
    *(uint4*)&rp[(2 ^ (j & 7)) * 8] = z4;
    *(uint4*)&rp[(3 ^ (j & 7)) * 8] = z4;
  }

  float dx = 0.f, dy = 0.f, dz = 0.f;
  f32x4 acc[4][2];

  for (int c = 0; c < 8; ++c) {
    // ---- enc + rel*ma: full wave; half 0 = sin+rd+relma, half 1 = cos ----
    {
      const int j = lane & 31;
      const int half = lane >> 5;
      const int jg = c * 128 + w * 32 + j;
      const float rx = cix - coors[jg * 3 + 0];
      const float ry = ciy - coors[jg * 3 + 1];
      const float rz = ciz - coors[jg * 3 + 2];
      const float rd = rx * rx + ry * ry + rz * rz;
      unsigned short* rp = &buf[w][0][j][0];
      if (half == 0) {
        const float ma = meanattn[i * N + jg];
        relma[w][j] = make_float4(ma * rx, ma * ry, ma * rz, 0.f);
        *(uint2*)&rp[(0 ^ (j & 7)) * 8] =
            make_uint2(pk2(__sinf(rd), __sinf(rd * 0.5f)),
                       pk2(__sinf(rd * 0.25f), __sinf(rd * 0.125f)));
        // k8 = rd, k9 = 1.0 (bias row in W1T)
        *(unsigned*)&rp[(1 ^ (j & 7)) * 8] = pk2(rd, 1.0f);
      } else {
        *(uint2*)&rp[((0 ^ (j & 7)) * 8) + 4] =
            make_uint2(pk2(__cosf(rd), __cosf(rd * 0.5f)),
                       pk2(__cosf(rd * 0.25f), __cosf(rd * 0.125f)));
      }
    }

    // ---- GEMM1: h1T = W1T @ encT  (K=32, bias via k=9) ----
#pragma unroll
    for (int mt = 0; mt < 4; ++mt)
#pragma unroll
      for (int nt = 0; nt < 2; ++nt)
        acc[mt][nt] = (f32x4){0.f, 0.f, 0.f, 0.f};
    {
      const int j0 = l15, j1 = 16 + l15;
      bf16x8 bf0 = *(const bf16x8*)&buf[w][0][j0][(lg ^ (j0 & 7)) * 8];
      bf16x8 bf1 = *(const bf16x8*)&buf[w][0][j1][(lg ^ (j1 & 7)) * 8];
#pragma unroll
      for (int mt = 0; mt < 4; ++mt) {
        acc[mt][0] = __builtin_amdgcn_mfma_f32_16x16x32_bf16(wf[mt], bf0, acc[mt][0], 0, 0, 0);
        acc[mt][1] = __builtin_amdgcn_mfma_f32_16x16x32_bf16(wf[mt], bf1, acc[mt][1], 0, 0, 0);
      }
    }
    // silu -> slot1
#pragma unroll
    for (int mt = 0; mt < 4; ++mt)
#pragma unroll
      for (int nt = 0; nt < 2; ++nt) {
        const f32x4 a = acc[mt][nt];
        const unsigned lo = pk2(silu_f(a[0]), silu_f(a[1]));
        const unsigned hi = pk2(silu_f(a[2]), silu_f(a[3]));
        const int j = nt * 16 + l15;
        const int g = mt * 2 + (lg >> 1);
        *(uint2*)&buf[w][1][j][((g ^ (j & 7)) * 8) + (lg & 1) * 4] = make_uint2(lo, hi);
      }

    // ---- merged GEMM: h2T = Wc^T @ h1T  (K=64, b2 & cb1 folded into b3v) ----
#pragma unroll
    for (int mt = 0; mt < 4; ++mt)
#pragma unroll
      for (int nt = 0; nt < 2; ++nt)
        acc[mt][nt] = (f32x4){b3v[mt * 4 + 0], b3v[mt * 4 + 1], b3v[mt * 4 + 2], b3v[mt * 4 + 3]};
#pragma unroll
    for (int ks = 0; ks < 2; ++ks) {
      const int gi = ks * 4 + lg;
      const int j0 = l15, j1 = 16 + l15;
      bf16x8 bf0 = *(const bf16x8*)&buf[w][1][j0][(gi ^ (j0 & 7)) * 8];
      bf16x8 bf1 = *(const bf16x8*)&buf[w][1][j1][(gi ^ (j1 & 7)) * 8];
#pragma unroll
      for (int mt = 0; mt < 4; ++mt) {
        acc[mt][0] = __builtin_amdgcn_mfma_f32_16x16x32_bf16(wf[4 + mt * 2 + ks], bf0, acc[mt][0], 0, 0, 0);
        acc[mt][1] = __builtin_amdgcn_mfma_f32_16x16x32_bf16(wf[4 + mt * 2 + ks], bf1, acc[mt][1], 0, 0, 0);
      }
    }

    // ---- epilogue: cw partial dot + delta accumulate ----
#pragma unroll
    for (int nt = 0; nt < 2; ++nt) {
      float cwp = cb2q;
#pragma unroll
      for (int mt = 0; mt < 4; ++mt) {
        const f32x4 a = acc[mt][nt];
#pragma unroll
        for (int r = 0; r < 4; ++r) cwp += silu_f(a[r]) * c2v[mt * 4 + r];
      }
      const float4 rm = relma[w][nt * 16 + l15];
      dx += cwp * rm.x;
      dy += cwp * rm.y;
      dz += cwp * rm.z;
    }
  }

  // reduce delta across wave, then block
#pragma unroll
  for (int off = 1; off < 64; off <<= 1) {
    dx += __shfl_xor(dx, off);
    dy += __shfl_xor(dy, off);
    dz += __shfl_xor(dz, off);
  }
  if (lane == 0) { redb[w][0] = dx; redb[w][1] = dy; redb[w][2] = dz; }
  __syncthreads();
  if (t == 0) {
    const float gg = gate[i];
    const float sx = redb[0][0] + redb[1][0] + redb[2][0] + redb[3][0];
    const float sy = redb[0][1] + redb[1][1] + redb[2][1] + redb[3][1];
    const float sz = redb[0][2] + redb[1][2] + redb[2][2] + redb[3][2];
    outc[i * 3 + 0] = cix + sx * gg;
    outc[i * 3 + 1] = ciy + sy * gg;
    outc[i * 3 + 2] = ciz + sz * gg;
  }
}

extern "C" void kernel_launch(void* const* d_in, const int* in_sizes, int n_in,
                              void* d_out, int out_size, void* d_ws, size_t ws_size,
                              hipStream_t stream) {
  const float* feats = (const float*)d_in[0];
  const float* coors = (const float*)d_in[1];
  const float* qkv_w = (const float*)d_in[2];
  const float* out_w = (const float*)d_in[3];
  const float* out_b = (const float*)d_in[4];
  const float* ew1 = (const float*)d_in[5];
  const float* eb1 = (const float*)d_in[6];
  const float* ew2 = (const float*)d_in[7];
  const float* eb2 = (const float*)d_in[8];
  const float* cw1 = (const float*)d_in[9];
  const float* cb1 = (const float*)d_in[10];
  const float* cw2 = (const float*)d_in[11];
  const float* cb2 = (const float*)d_in[12];
  const float* gw1 = (const float*)d_in[13];
  const float* gb1 = (const float*)d_in[14];
  const float* gw2 = (const float*)d_in[15];
  const float* gb2 = (const float*)d_in[16];
  const float* ln1_g = (const float*)d_in[17];
  const float* ln1_b = (const float*)d_in[18];
  const float* ln2_g = (const float*)d_in[19];
  const float* ln2_b = (const float*)d_in[20];
  const float* fw1 = (const float*)d_in[21];
  const float* fb1 = (const float*)d_in[22];
  const float* fw2 = (const float*)d_in[23];
  const float* fb2 = (const float*)d_in[24];

  float* ws = (float*)d_ws;
  float* xn = ws;                         // 65536
  float* qkv = ws + 65536;                // 196608
  float* x1 = ws + 262144;                // 65536
  float* gate = ws + 327680;              // 1024
  unsigned short* pw = (unsigned short*)(ws + 328704);  // 6144 ushort used (region 5120 floats)
  float* b3p = ws + 333824;               // 64
  float* meanattn = ws + 333888;          // 1048576

  float* xout = (float*)d_out;
  float* coorout = xout + 65536;

  hipLaunchKernelGGL(k_ln1_qkv, dim3(N), dim3(64), 0, stream, feats, ln1_g, ln1_b, qkv_w, xn, qkv);
  hipLaunchKernelGGL(k_prep, dim3(1), dim3(256), 0, stream, ew1, eb1, ew2, cw1, eb2, cb1, pw, b3p);
  hipLaunchKernelGGL(k_attn, dim3(N), dim3(256), 0, stream, qkv, xn, out_w, out_b, x1, meanattn);
  hipLaunchKernelGGL(k_ffn_gate, dim3(N), dim3(256), 0, stream, x1, ln2_g, ln2_b,
                     fw1, fb1, fw2, fb2, gw1, gb1, gw2, gb2, xout, gate);
  hipLaunchKernelGGL(k_pair, dim3(N), dim3(256), 0, stream, coors, meanattn, pw,
                     b3p, cw2, cb2, gate, coorout);
}